// Round 2
// baseline (450.449 us; speedup 1.0000x reference)
//
#include <hip/hip_runtime.h>

typedef unsigned short u16;
typedef __bf16 bf16_t;
typedef bf16_t bf16x8 __attribute__((ext_vector_type(8)));
typedef float floatx4 __attribute__((ext_vector_type(4)));

static constexpr float kScale = 0.014731391274719741f;    // 1/sqrt(512*9)
static constexpr float kScale2 = 2.1701388888888894e-4f;  // 1/(512*9)
static constexpr float kLinScale = 0.044194173824159216f; // 1/sqrt(512)

__device__ __forceinline__ u16 f2bf(float f) {
  unsigned u = __float_as_uint(f);
  u += 0x7FFFu + ((u >> 16) & 1u);
  return (u16)(u >> 16);
}

// async 16B global->LDS; LDS dst semantics: wave-uniform base + lane*16
#define GLD16(g, l)                                                        \
  __builtin_amdgcn_global_load_lds(                                        \
      (const __attribute__((address_space(1))) unsigned int*)(g),          \
      (__attribute__((address_space(3))) unsigned int*)(l), 16, 0, 0)

// ---------------------------------------------------------------------------
// Fused prep: blocks [0,1024): s[b,c] = style.modw^T*lin + bias
//             blocks [1024,2048): ssq[o,c] = sum_tap w^2
__global__ __launch_bounds__(256) void k_prep1(const float* __restrict__ style,
                                               const float* __restrict__ modw,
                                               const float* __restrict__ modb,
                                               const float* __restrict__ weight,
                                               float* __restrict__ s_buf,
                                               float* __restrict__ ssq) {
  int tid = threadIdx.x;
  if (blockIdx.x < 1024) {
    int lane = tid & 63, wv = tid >> 6;
    int idx = blockIdx.x * 4 + wv; // [0,4096)
    int b = idx >> 9, c = idx & 511;
    const float* st = style + b * 512;
    const float* mw = modw + (size_t)c * 512;
    float s = 0.f;
#pragma unroll
    for (int i = 0; i < 8; ++i) s += st[lane + i * 64] * mw[lane + i * 64];
#pragma unroll
    for (int off = 32; off; off >>= 1) s += __shfl_xor(s, off);
    if (lane == 0) s_buf[idx] = s * kLinScale + modb[c];
  } else {
    int e = (blockIdx.x - 1024) * 256 + tid; // [0, 262144)
    const float* wp = weight + (size_t)e * 9;
    float ss = 0.f;
#pragma unroll
    for (int t = 0; t < 9; ++t) ss += wp[t] * wp[t];
    ssq[e] = ss;
  }
}

// ---------------------------------------------------------------------------
// demod[b,o] = rsqrt( kScale^2 * sum_c ssq[o,c]*s[b,c]^2 + eps )
__global__ __launch_bounds__(256) void k_demod2(const float* __restrict__ ssq,
                                                const float* __restrict__ s_buf,
                                                float* __restrict__ demod_buf) {
  int tid = threadIdx.x, lane = tid & 63, wv = tid >> 6;
  int idx = blockIdx.x * 4 + wv; // [0,4096)
  int b = idx >> 9, o = idx & 511;
  const float* sq = ssq + (size_t)o * 512;
  const float* srow = s_buf + b * 512;
  float ss = 0.f;
#pragma unroll
  for (int i = 0; i < 8; ++i) {
    float s = srow[lane + i * 64];
    ss += sq[lane + i * 64] * s * s;
  }
#pragma unroll
  for (int off = 32; off; off >>= 1) ss += __shfl_xor(ss, off);
  if (lane == 0) demod_buf[idx] = rsqrtf(ss * kScale2 + 1e-8f);
}

// ---------------------------------------------------------------------------
// NCHW f32 -> NHWC bf16 with fused per-channel modulation:
// in_t[b,y,x,c] = bf16( in[b,c,y,x] * s[b,c] )
__global__ __launch_bounds__(256) void k_transpose(const float* __restrict__ in,
                                                   const float* __restrict__ s_buf,
                                                   unsigned* __restrict__ in_t32) {
  __shared__ u16 tile[64 * 65];
  int tid = threadIdx.x;
  int c0 = blockIdx.x * 64, y = blockIdx.y, b = blockIdx.z;
  const float* src = in + ((size_t)(b * 512 + c0) * 4096) + y * 64;
  const float* srow = s_buf + b * 512 + c0;
#pragma unroll
  for (int it = 0; it < 16; ++it) {
    int idx = it * 256 + tid;
    int cl = idx >> 6, x = idx & 63;
    tile[cl * 65 + x] = f2bf(src[(size_t)cl * 4096 + x] * srow[cl]);
  }
  __syncthreads();
  unsigned* dst = in_t32 + ((size_t)(b * 64 + y) * 64) * 256 + (c0 >> 1);
#pragma unroll
  for (int it = 0; it < 8; ++it) {
    int flat = it * 256 + tid; // [0,2048)
    int cl2 = flat & 31, x = flat >> 5;
    unsigned lo = tile[(2 * cl2) * 65 + x];
    unsigned hi = tile[(2 * cl2 + 1) * 65 + x];
    dst[(size_t)x * 256 + cl2] = lo | (hi << 16);
  }
}

// ---------------------------------------------------------------------------
// Batch-independent weight fragments: w_frag[tap][ct][ot][512] = kScale * w,
// pos = (o_l + 16*(c_l>>3))*8 + (c_l&7). Only 4.7 MB.
__global__ __launch_bounds__(256) void k_wfrag(const float* __restrict__ weight,
                                               unsigned* __restrict__ wt32) {
  __shared__ u16 tiles[9][512];
  int tid = threadIdx.x;
  int ct = blockIdx.x, ot = blockIdx.y;
  int o0 = ot * 16, c0 = ct * 32;
#pragma unroll
  for (int i = 0; i < 18; ++i) {
    int flat = i * 256 + tid;         // [0,4608) = o_l*288 + c_l*9 + tap
    int t9 = flat / 9;
    int tap = flat - t9 * 9;
    int o_l = t9 >> 5, c_l = t9 & 31;
    float w = weight[((size_t)(o0 + o_l) * 512 + c0 + c_l) * 9 + tap];
    int pos = ((o_l + ((c_l >> 3) << 4)) << 3) + (c_l & 7);
    tiles[tap][pos] = f2bf(w * kScale);
  }
  __syncthreads();
  const unsigned* tl = (const unsigned*)tiles;
#pragma unroll
  for (int tap = 0; tap < 9; ++tap)
    wt32[(size_t)((tap * 16 + ct) * 32 + ot) * 256 + tid] = tl[tap * 256 + tid];
}

// ---------------------------------------------------------------------------
// Implicit-GEMM conv. LDS-BW fix: A fragments read DIRECTLY from global
// (w_t is 4.7 MB, L2-resident; layout mirrors old LDS layout 1:1), halving
// LDS read traffic. LDS = 2 x 16 KB B double-buffer only -> 4 blocks/CU
// (VGPR capped at 128 via __launch_bounds__(256,4)). One barrier per ct.
// A loads software-pipelined one tap ahead (t=8 prefetch crosses barrier).
// XCD swizzle: linear id & 7 = batch b, so each XCD owns one image.
__global__ __launch_bounds__(256, 4) void k_conv(const u16* __restrict__ in_t,
                                                 const u16* __restrict__ w_t,
                                                 const float* __restrict__ demod_buf,
                                                 float* __restrict__ out) {
  __shared__ char smem[32768]; // B: 2 x 16 KB
  const int tid = threadIdx.x;
  const int lane = tid & 63;
  const int wv = tid >> 6;
  const int wm = wv >> 1, wn = wv & 1;
  const int quad = lane >> 4, m16 = lane & 15;
  // decode linear block id; lin & 7 selects XCD (round-robin dispatch) = batch
  const int lin = blockIdx.x + 32 * blockIdx.y + 128 * blockIdx.z; // [0,1024)
  const int b = lin & 7;
  const int r_ = lin >> 3;   // [0,128)
  const int nt = r_ & 31;
  const int mt = r_ >> 5;    // [0,4)
  const int y0 = nt * 2;

  floatx4 acc[4][4];
#pragma unroll
  for (int i = 0; i < 4; ++i)
#pragma unroll
    for (int j = 0; j < 4; ++j) acc[i][j] = (floatx4){0.f, 0.f, 0.f, 0.f};

  // per-lane A base (u16 elements); af(tap,ct,ms) = abase + ((tap*16+ct)<<14) + ms*512
  const u16* abase = w_t + mt * 4096 + wm * 2048 + lane * 8;

// async-stage B tile for channel-tile ct_ into LDS buffer Bbuf
#define STAGE_B(ct_, Bbuf)                                                   \
  {                                                                          \
    const int c0s = (ct_)*32;                                                \
    _Pragma("unroll") for (int r = 0; r < 4; ++r) {                          \
      const int ci = r * 256 + tid;                                          \
      const int s = ci >> 2, qi = ci & 3;                                    \
      const int x = s & 63;                                                  \
      const int y = y0 - 1 + r;                                              \
      const int qd = qi ^ (x & 3);                                           \
      char* lbase = (Bbuf) + (r * 4 + wv) * 1024;                            \
      if ((unsigned)y < 64u) {                                               \
        const u16* g =                                                       \
            in_t + (((size_t)(b * 64 + y) * 64 + x) * 512 + c0s + qd * 8);   \
        GLD16(g, lbase);                                                     \
      } else {                                                               \
        *(uint4*)((Bbuf) + ci * 16) = make_uint4(0u, 0u, 0u, 0u);            \
      }                                                                      \
    }                                                                        \
  }

  // ---- prologue ----
  STAGE_B(0, smem);
  bf16x8 afc[4];
#pragma unroll
  for (int ms = 0; ms < 4; ++ms)
    afc[ms] = *(const bf16x8*)(abase + ms * 512); // (tap=0, ct=0)
  __syncthreads();

  int cur = 0;
  for (int ct = 0; ct < 16; ++ct) {
    char* Bs = smem + cur * 16384;
    char* Bn = smem + (cur ^ 1) * 16384;
    if (ct < 15) STAGE_B(ct + 1, Bn);
#pragma unroll
    for (int t = 0; t < 9; ++t) {
      const int dy = t / 3, dx = t % 3;
      // prefetch A for next tap (t=8: first tap of next ct, crosses barrier)
      const int tn = (t == 8) ? 0 : t + 1;
      const int ctn = (t == 8) ? ((ct + 1) & 15) : ct;
      const u16* apn = abase + ((size_t)(tn * 16 + ctn) << 14);
      bf16x8 afn[4];
#pragma unroll
      for (int ms = 0; ms < 4; ++ms)
        afn[ms] = *(const bf16x8*)(apn + ms * 512);
      __builtin_amdgcn_s_setprio(1);
#pragma unroll
      for (int ns = 0; ns < 4; ++ns) {
        const int nl = wn * 64 + ns * 16 + m16;
        const int ly = nl >> 6, lx = nl & 63;
        const int sx = lx + dx - 1;
        bf16x8 bv;
        if ((unsigned)sx < 64u) {
          const int s = (ly + dy) * 64 + sx;
          bv = *(const bf16x8*)(Bs + s * 64 + ((quad ^ (sx & 3)) << 4));
        } else {
#pragma unroll
          for (int j = 0; j < 8; ++j) bv[j] = (bf16_t)0.f;
        }
#pragma unroll
        for (int ms = 0; ms < 4; ++ms)
          acc[ms][ns] = __builtin_amdgcn_mfma_f32_16x16x32_bf16(
              afc[ms], bv, acc[ms][ns], 0, 0, 0);
      }
      __builtin_amdgcn_s_setprio(0);
#pragma unroll
      for (int ms = 0; ms < 4; ++ms) afc[ms] = afn[ms];
    }
    __syncthreads(); // drains B(ct+1) loads; all reads of Bs done -> swap
    cur ^= 1;
  }

#undef STAGE_B

  // epilogue: D[m=quad*4+r][n=lane&15], scale by demod[b,o], f32 out
  const int ob = mt * 128 + wm * 64;
  const int nb = nt * 128 + wn * 64;
#pragma unroll
  for (int ms = 0; ms < 4; ++ms)
#pragma unroll
    for (int ns = 0; ns < 4; ++ns) {
      const int n = nb + ns * 16 + m16;
#pragma unroll
      for (int r = 0; r < 4; ++r) {
        const int o = ob + ms * 16 + quad * 4 + r;
        float dm = demod_buf[b * 512 + o];
        out[((size_t)(b * 512 + o) << 12) + n] = acc[ms][ns][r] * dm;
      }
    }
}

// ---------------------------------------------------------------------------
extern "C" void kernel_launch(void* const* d_in, const int* in_sizes, int n_in,
                              void* d_out, int out_size, void* d_ws, size_t ws_size,
                              hipStream_t stream) {
  const float* input = (const float*)d_in[0];   // [8,512,64,64] f32
  const float* style = (const float*)d_in[1];   // [8,512] f32
  const float* weight = (const float*)d_in[2];  // [1,512,512,3,3] f32
  const float* modw = (const float*)d_in[3];    // [512,512] f32
  const float* modb = (const float*)d_in[4];    // [512] f32
  float* out = (float*)d_out;                   // [8,512,64,64] f32
  char* ws = (char*)d_ws;
  float* s_buf = (float*)ws;                             // 16 KB
  float* demod_buf = (float*)(ws + 16384);               // 16 KB
  float* ssq = (float*)(ws + 32768);                     // 1 MB
  u16* in_t = (u16*)(ws + 32768 + 1048576);              // NHWC bf16, 33.5 MB
  u16* w_t = (u16*)(ws + 32768 + 1048576 + 33554432);    // frag bf16, 4.7 MB

  k_prep1<<<dim3(2048), dim3(256), 0, stream>>>(style, modw, modb, weight, s_buf, ssq);
  k_demod2<<<dim3(1024), dim3(256), 0, stream>>>(ssq, s_buf, demod_buf);
  k_transpose<<<dim3(8, 64, 8), dim3(256), 0, stream>>>(input, s_buf, (unsigned*)in_t);
  k_wfrag<<<dim3(16, 32), dim3(256), 0, stream>>>(weight, (unsigned*)w_t);
  k_conv<<<dim3(32, 4, 8), dim3(256), 0, stream>>>(in_t, w_t, demod_buf, out);
}

// Round 3
// 256.068 us; speedup vs baseline: 1.7591x; 1.7591x over previous
//
#include <hip/hip_runtime.h>

typedef unsigned short u16;
typedef __bf16 bf16_t;
typedef bf16_t bf16x8 __attribute__((ext_vector_type(8)));
typedef float floatx4 __attribute__((ext_vector_type(4)));

static constexpr float kScale = 0.014731391274719741f;    // 1/sqrt(512*9)
static constexpr float kScale2 = 2.1701388888888894e-4f;  // 1/(512*9)
static constexpr float kLinScale = 0.044194173824159216f; // 1/sqrt(512)

__device__ __forceinline__ u16 f2bf(float f) {
  unsigned u = __float_as_uint(f);
  u += 0x7FFFu + ((u >> 16) & 1u);
  return (u16)(u >> 16);
}

// async 16B global->LDS; LDS dst semantics: wave-uniform base + lane*16
#define GLD16(g, l)                                                        \
  __builtin_amdgcn_global_load_lds(                                        \
      (const __attribute__((address_space(1))) unsigned int*)(g),          \
      (__attribute__((address_space(3))) unsigned int*)(l), 16, 0, 0)

// ---------------------------------------------------------------------------
// Fused prep: blocks [0,1024): s[b,c] = style.modw^T*lin + bias
//             blocks [1024,2048): ssq[o,c] = sum_tap w^2
__global__ __launch_bounds__(256) void k_prep1(const float* __restrict__ style,
                                               const float* __restrict__ modw,
                                               const float* __restrict__ modb,
                                               const float* __restrict__ weight,
                                               float* __restrict__ s_buf,
                                               float* __restrict__ ssq) {
  int tid = threadIdx.x;
  if (blockIdx.x < 1024) {
    int lane = tid & 63, wv = tid >> 6;
    int idx = blockIdx.x * 4 + wv; // [0,4096)
    int b = idx >> 9, c = idx & 511;
    const float* st = style + b * 512;
    const float* mw = modw + (size_t)c * 512;
    float s = 0.f;
#pragma unroll
    for (int i = 0; i < 8; ++i) s += st[lane + i * 64] * mw[lane + i * 64];
#pragma unroll
    for (int off = 32; off; off >>= 1) s += __shfl_xor(s, off);
    if (lane == 0) s_buf[idx] = s * kLinScale + modb[c];
  } else {
    int e = (blockIdx.x - 1024) * 256 + tid; // [0, 262144)
    const float* wp = weight + (size_t)e * 9;
    float ss = 0.f;
#pragma unroll
    for (int t = 0; t < 9; ++t) ss += wp[t] * wp[t];
    ssq[e] = ss;
  }
}

// ---------------------------------------------------------------------------
// demod[b,o] = rsqrt( kScale^2 * sum_c ssq[o,c]*s[b,c]^2 + eps )
__global__ __launch_bounds__(256) void k_demod2(const float* __restrict__ ssq,
                                                const float* __restrict__ s_buf,
                                                float* __restrict__ demod_buf) {
  int tid = threadIdx.x, lane = tid & 63, wv = tid >> 6;
  int idx = blockIdx.x * 4 + wv; // [0,4096)
  int b = idx >> 9, o = idx & 511;
  const float* sq = ssq + (size_t)o * 512;
  const float* srow = s_buf + b * 512;
  float ss = 0.f;
#pragma unroll
  for (int i = 0; i < 8; ++i) {
    float s = srow[lane + i * 64];
    ss += sq[lane + i * 64] * s * s;
  }
#pragma unroll
  for (int off = 32; off; off >>= 1) ss += __shfl_xor(ss, off);
  if (lane == 0) demod_buf[idx] = rsqrtf(ss * kScale2 + 1e-8f);
}

// ---------------------------------------------------------------------------
// NCHW f32 -> NHWC bf16 with fused per-channel modulation:
// in_t[b,y,x,c] = bf16( in[b,c,y,x] * s[b,c] )
__global__ __launch_bounds__(256) void k_transpose(const float* __restrict__ in,
                                                   const float* __restrict__ s_buf,
                                                   unsigned* __restrict__ in_t32) {
  __shared__ u16 tile[64 * 65];
  int tid = threadIdx.x;
  int c0 = blockIdx.x * 64, y = blockIdx.y, b = blockIdx.z;
  const float* src = in + ((size_t)(b * 512 + c0) * 4096) + y * 64;
  const float* srow = s_buf + b * 512 + c0;
#pragma unroll
  for (int it = 0; it < 16; ++it) {
    int idx = it * 256 + tid;
    int cl = idx >> 6, x = idx & 63;
    tile[cl * 65 + x] = f2bf(src[(size_t)cl * 4096 + x] * srow[cl]);
  }
  __syncthreads();
  unsigned* dst = in_t32 + ((size_t)(b * 64 + y) * 64) * 256 + (c0 >> 1);
#pragma unroll
  for (int it = 0; it < 8; ++it) {
    int flat = it * 256 + tid; // [0,2048)
    int cl2 = flat & 31, x = flat >> 5;
    unsigned lo = tile[(2 * cl2) * 65 + x];
    unsigned hi = tile[(2 * cl2 + 1) * 65 + x];
    dst[(size_t)x * 256 + cl2] = lo | (hi << 16);
  }
}

// ---------------------------------------------------------------------------
// Batch-independent weight fragments: w_frag[tap][ct][ot][512] = kScale * w,
// pos = (o_l + 16*(c_l>>3))*8 + (c_l&7). Only 4.7 MB.
__global__ __launch_bounds__(256) void k_wfrag(const float* __restrict__ weight,
                                               unsigned* __restrict__ wt32) {
  __shared__ u16 tiles[9][512];
  int tid = threadIdx.x;
  int ct = blockIdx.x, ot = blockIdx.y;
  int o0 = ot * 16, c0 = ct * 32;
#pragma unroll
  for (int i = 0; i < 18; ++i) {
    int flat = i * 256 + tid;         // [0,4608) = o_l*288 + c_l*9 + tap
    int t9 = flat / 9;
    int tap = flat - t9 * 9;
    int o_l = t9 >> 5, c_l = t9 & 31;
    float w = weight[((size_t)(o0 + o_l) * 512 + c0 + c_l) * 9 + tap];
    int pos = ((o_l + ((c_l >> 3) << 4)) << 3) + (c_l & 7);
    tiles[tap][pos] = f2bf(w * kScale);
  }
  __syncthreads();
  const unsigned* tl = (const unsigned*)tiles;
#pragma unroll
  for (int tap = 0; tap < 9; ++tap)
    wt32[(size_t)((tap * 16 + ct) * 32 + ot) * 256 + tid] = tl[tap * 256 + tid];
}

// ---------------------------------------------------------------------------
// Implicit-GEMM conv. A fragments read DIRECTLY from global (w_t is 4.7 MB,
// L2/L3-resident; 8 KB/block per (tap,ct), shared by 32 nt-blocks per XCD),
// halving LDS read traffic vs R1. LDS = 2 x 16 KB B double-buffer only.
// __launch_bounds__(256,2): 256 unified VGPR+AGPR budget -- acc(64 AGPR) +
// 3-deep A-ring(48 VGPR) + addressing fits with NO spill (R2's bug was the
// 128 budget from min-waves=4 -> scratch thrash).
// A prefetch depth 2 (ring of 3, fully unrolled -> compile-time indices).
// One barrier per ct. XCD swizzle: lin&7 = batch b -> per-XCD L2 locality.
__global__ __launch_bounds__(256, 2) void k_conv(const u16* __restrict__ in_t,
                                                 const u16* __restrict__ w_t,
                                                 const float* __restrict__ demod_buf,
                                                 float* __restrict__ out) {
  __shared__ char smem[32768]; // B: 2 x 16 KB
  const int tid = threadIdx.x;
  const int lane = tid & 63;
  const int wv = tid >> 6;
  const int wm = wv >> 1, wn = wv & 1;
  const int quad = lane >> 4, m16 = lane & 15;
  // decode linear block id; lin & 7 selects XCD (round-robin dispatch) = batch
  const int lin = blockIdx.x + 32 * blockIdx.y + 128 * blockIdx.z; // [0,1024)
  const int b = lin & 7;
  const int r_ = lin >> 3;   // [0,128)
  const int nt = r_ & 31;
  const int mt = r_ >> 5;    // [0,4)
  const int y0 = nt * 2;

  floatx4 acc[4][4];
#pragma unroll
  for (int i = 0; i < 4; ++i)
#pragma unroll
    for (int j = 0; j < 4; ++j) acc[i][j] = (floatx4){0.f, 0.f, 0.f, 0.f};

  // per-lane A base (u16 elements); af(tap,ct,ms) = abase + ((tap*16+ct)<<14) + ms*512
  const u16* abase = w_t + mt * 4096 + wm * 2048 + lane * 8;

// async-stage B tile for channel-tile ct_ into LDS buffer Bbuf
#define STAGE_B(ct_, Bbuf)                                                   \
  {                                                                          \
    const int c0s = (ct_)*32;                                                \
    _Pragma("unroll") for (int r = 0; r < 4; ++r) {                          \
      const int ci = r * 256 + tid;                                          \
      const int s = ci >> 2, qi = ci & 3;                                    \
      const int x = s & 63;                                                  \
      const int y = y0 - 1 + r;                                              \
      const int qd = qi ^ (x & 3);                                           \
      char* lbase = (Bbuf) + (r * 4 + wv) * 1024;                            \
      if ((unsigned)y < 64u) {                                               \
        const u16* g =                                                       \
            in_t + (((size_t)(b * 64 + y) * 64 + x) * 512 + c0s + qd * 8);   \
        GLD16(g, lbase);                                                     \
      } else {                                                               \
        *(uint4*)((Bbuf) + ci * 16) = make_uint4(0u, 0u, 0u, 0u);            \
      }                                                                      \
    }                                                                        \
  }

// load A fragments (4 x bf16x8) for (tap_, ct_) into ring slot dst
#define LOAD_A(tap_, ct_, dst)                                               \
  {                                                                          \
    const u16* ap_ = abase + ((size_t)((tap_)*16 + (ct_)) << 14);            \
    _Pragma("unroll") for (int ms = 0; ms < 4; ++ms)                         \
      (dst)[ms] = *(const bf16x8*)(ap_ + ms * 512);                          \
  }

  // ---- prologue: B(0) staged; A taps 0,1 of ct 0 in flight ----
  STAGE_B(0, smem);
  bf16x8 aR0[4], aR1[4], aR2[4];
  LOAD_A(0, 0, aR0);
  LOAD_A(1, 0, aR1);
  __syncthreads();

  int cur = 0;
  for (int ct = 0; ct < 16; ++ct) {
    char* Bs = smem + cur * 16384;
    char* Bn = smem + (cur ^ 1) * 16384;
    if (ct < 15) STAGE_B(ct + 1, Bn);
#pragma unroll
    for (int t = 0; t < 9; ++t) {
      const int dy = t / 3, dx = t % 3;
      // prefetch A two taps ahead (t=7,8 cross into next ct's taps 0,1)
      const int tp = (t + 2 <= 8) ? t + 2 : t - 7;
      const int ctp = (t + 2 <= 8) ? ct : ((ct + 1) & 15);
      if (t % 3 == 0) {
        LOAD_A(tp, ctp, aR2);
      } else if (t % 3 == 1) {
        LOAD_A(tp, ctp, aR0);
      } else {
        LOAD_A(tp, ctp, aR1);
      }
      const bf16x8* afc = (t % 3 == 0) ? aR0 : (t % 3 == 1) ? aR1 : aR2;
      __builtin_amdgcn_s_setprio(1);
#pragma unroll
      for (int ns = 0; ns < 4; ++ns) {
        const int nl = wn * 64 + ns * 16 + m16;
        const int ly = nl >> 6, lx = nl & 63;
        const int sx = lx + dx - 1;
        bf16x8 bv;
        if ((unsigned)sx < 64u) {
          const int s = (ly + dy) * 64 + sx;
          bv = *(const bf16x8*)(Bs + s * 64 + ((quad ^ (sx & 3)) << 4));
        } else {
#pragma unroll
          for (int j = 0; j < 8; ++j) bv[j] = (bf16_t)0.f;
        }
#pragma unroll
        for (int ms = 0; ms < 4; ++ms)
          acc[ms][ns] = __builtin_amdgcn_mfma_f32_16x16x32_bf16(
              afc[ms], bv, acc[ms][ns], 0, 0, 0);
      }
      __builtin_amdgcn_s_setprio(0);
    }
    __syncthreads(); // drains B(ct+1) loads; all reads of Bs done -> swap
    cur ^= 1;
  }

#undef STAGE_B
#undef LOAD_A

  // epilogue: D[m=quad*4+r][n=lane&15], scale by demod[b,o], f32 out
  const int ob = mt * 128 + wm * 64;
  const int nb = nt * 128 + wn * 64;
#pragma unroll
  for (int ms = 0; ms < 4; ++ms)
#pragma unroll
    for (int ns = 0; ns < 4; ++ns) {
      const int n = nb + ns * 16 + m16;
#pragma unroll
      for (int r = 0; r < 4; ++r) {
        const int o = ob + ms * 16 + quad * 4 + r;
        float dm = demod_buf[b * 512 + o];
        out[((size_t)(b * 512 + o) << 12) + n] = acc[ms][ns][r] * dm;
      }
    }
}

// ---------------------------------------------------------------------------
extern "C" void kernel_launch(void* const* d_in, const int* in_sizes, int n_in,
                              void* d_out, int out_size, void* d_ws, size_t ws_size,
                              hipStream_t stream) {
  const float* input = (const float*)d_in[0];   // [8,512,64,64] f32
  const float* style = (const float*)d_in[1];   // [8,512] f32
  const float* weight = (const float*)d_in[2];  // [1,512,512,3,3] f32
  const float* modw = (const float*)d_in[3];    // [512,512] f32
  const float* modb = (const float*)d_in[4];    // [512] f32
  float* out = (float*)d_out;                   // [8,512,64,64] f32
  char* ws = (char*)d_ws;
  float* s_buf = (float*)ws;                             // 16 KB
  float* demod_buf = (float*)(ws + 16384);               // 16 KB
  float* ssq = (float*)(ws + 32768);                     // 1 MB
  u16* in_t = (u16*)(ws + 32768 + 1048576);              // NHWC bf16, 33.5 MB
  u16* w_t = (u16*)(ws + 32768 + 1048576 + 33554432);    // frag bf16, 4.7 MB

  k_prep1<<<dim3(2048), dim3(256), 0, stream>>>(style, modw, modb, weight, s_buf, ssq);
  k_demod2<<<dim3(1024), dim3(256), 0, stream>>>(ssq, s_buf, demod_buf);
  k_transpose<<<dim3(8, 64, 8), dim3(256), 0, stream>>>(input, s_buf, (unsigned*)in_t);
  k_wfrag<<<dim3(16, 32), dim3(256), 0, stream>>>(weight, (unsigned*)w_t);
  k_conv<<<dim3(32, 4, 8), dim3(256), 0, stream>>>(in_t, w_t, demod_buf, out);
}

// Round 4
// 255.222 us; speedup vs baseline: 1.7649x; 1.0033x over previous
//
#include <hip/hip_runtime.h>

typedef unsigned short u16;
typedef __bf16 bf16_t;
typedef bf16_t bf16x8 __attribute__((ext_vector_type(8)));
typedef float floatx4 __attribute__((ext_vector_type(4)));

static constexpr float kScale = 0.014731391274719741f;    // 1/sqrt(512*9)
static constexpr float kScale2 = 2.1701388888888894e-4f;  // 1/(512*9)
static constexpr float kLinScale = 0.044194173824159216f; // 1/sqrt(512)

__device__ __forceinline__ u16 f2bf(float f) {
  unsigned u = __float_as_uint(f);
  u += 0x7FFFu + ((u >> 16) & 1u);
  return (u16)(u >> 16);
}

// async 16B global->LDS; LDS dst semantics: wave-uniform base + lane*16
#define GLD16(g, l)                                                        \
  __builtin_amdgcn_global_load_lds(                                        \
      (const __attribute__((address_space(1))) unsigned int*)(g),          \
      (__attribute__((address_space(3))) unsigned int*)(l), 16, 0, 0)

// ---------------------------------------------------------------------------
// Fused prep: blocks [0,1024): s[b,c] = style.modw^T*lin + bias
//             blocks [1024,2048): ssq[o,c] = sum_tap w^2
__global__ __launch_bounds__(256) void k_prep1(const float* __restrict__ style,
                                               const float* __restrict__ modw,
                                               const float* __restrict__ modb,
                                               const float* __restrict__ weight,
                                               float* __restrict__ s_buf,
                                               float* __restrict__ ssq) {
  int tid = threadIdx.x;
  if (blockIdx.x < 1024) {
    int lane = tid & 63, wv = tid >> 6;
    int idx = blockIdx.x * 4 + wv; // [0,4096)
    int b = idx >> 9, c = idx & 511;
    const float* st = style + b * 512;
    const float* mw = modw + (size_t)c * 512;
    float s = 0.f;
#pragma unroll
    for (int i = 0; i < 8; ++i) s += st[lane + i * 64] * mw[lane + i * 64];
#pragma unroll
    for (int off = 32; off; off >>= 1) s += __shfl_xor(s, off);
    if (lane == 0) s_buf[idx] = s * kLinScale + modb[c];
  } else {
    int e = (blockIdx.x - 1024) * 256 + tid; // [0, 262144)
    const float* wp = weight + (size_t)e * 9;
    float ss = 0.f;
#pragma unroll
    for (int t = 0; t < 9; ++t) ss += wp[t] * wp[t];
    ssq[e] = ss;
  }
}

// ---------------------------------------------------------------------------
// demod[b,o] = rsqrt( kScale^2 * sum_c ssq[o,c]*s[b,c]^2 + eps )
__global__ __launch_bounds__(256) void k_demod2(const float* __restrict__ ssq,
                                                const float* __restrict__ s_buf,
                                                float* __restrict__ demod_buf) {
  int tid = threadIdx.x, lane = tid & 63, wv = tid >> 6;
  int idx = blockIdx.x * 4 + wv; // [0,4096)
  int b = idx >> 9, o = idx & 511;
  const float* sq = ssq + (size_t)o * 512;
  const float* srow = s_buf + b * 512;
  float ss = 0.f;
#pragma unroll
  for (int i = 0; i < 8; ++i) {
    float s = srow[lane + i * 64];
    ss += sq[lane + i * 64] * s * s;
  }
#pragma unroll
  for (int off = 32; off; off >>= 1) ss += __shfl_xor(ss, off);
  if (lane == 0) demod_buf[idx] = rsqrtf(ss * kScale2 + 1e-8f);
}

// ---------------------------------------------------------------------------
// NCHW f32 -> NHWC bf16 with fused per-channel modulation:
// in_t[b,y,x,c] = bf16( in[b,c,y,x] * s[b,c] )
__global__ __launch_bounds__(256) void k_transpose(const float* __restrict__ in,
                                                   const float* __restrict__ s_buf,
                                                   unsigned* __restrict__ in_t32) {
  __shared__ u16 tile[64 * 65];
  int tid = threadIdx.x;
  int c0 = blockIdx.x * 64, y = blockIdx.y, b = blockIdx.z;
  const float* src = in + ((size_t)(b * 512 + c0) * 4096) + y * 64;
  const float* srow = s_buf + b * 512 + c0;
#pragma unroll
  for (int it = 0; it < 16; ++it) {
    int idx = it * 256 + tid;
    int cl = idx >> 6, x = idx & 63;
    tile[cl * 65 + x] = f2bf(src[(size_t)cl * 4096 + x] * srow[cl]);
  }
  __syncthreads();
  unsigned* dst = in_t32 + ((size_t)(b * 64 + y) * 64) * 256 + (c0 >> 1);
#pragma unroll
  for (int it = 0; it < 8; ++it) {
    int flat = it * 256 + tid; // [0,2048)
    int cl2 = flat & 31, x = flat >> 5;
    unsigned lo = tile[(2 * cl2) * 65 + x];
    unsigned hi = tile[(2 * cl2 + 1) * 65 + x];
    dst[(size_t)x * 256 + cl2] = lo | (hi << 16);
  }
}

// ---------------------------------------------------------------------------
// Batch-independent weight fragments: w_frag[tap][ct][ot][512] = kScale * w,
// pos = (o_l + 16*(c_l>>3))*8 + (c_l&7). Only 4.7 MB.
__global__ __launch_bounds__(256) void k_wfrag(const float* __restrict__ weight,
                                               unsigned* __restrict__ wt32) {
  __shared__ u16 tiles[9][512];
  int tid = threadIdx.x;
  int ct = blockIdx.x, ot = blockIdx.y;
  int o0 = ot * 16, c0 = ct * 32;
#pragma unroll
  for (int i = 0; i < 18; ++i) {
    int flat = i * 256 + tid;         // [0,4608) = o_l*288 + c_l*9 + tap
    int t9 = flat / 9;
    int tap = flat - t9 * 9;
    int o_l = t9 >> 5, c_l = t9 & 31;
    float w = weight[((size_t)(o0 + o_l) * 512 + c0 + c_l) * 9 + tap];
    int pos = ((o_l + ((c_l >> 3) << 4)) << 3) + (c_l & 7);
    tiles[tap][pos] = f2bf(w * kScale);
  }
  __syncthreads();
  const unsigned* tl = (const unsigned*)tiles;
#pragma unroll
  for (int tap = 0; tap < 9; ++tap)
    wt32[(size_t)((tap * 16 + ct) * 32 + ot) * 256 + tid] = tl[tap * 256 + tid];
}

// ---------------------------------------------------------------------------
// Implicit-GEMM conv. A fragments from L2-resident w_t (no LDS). B tiles in
// LDS, TRIPLE-buffered (3 x 16 KB); B fragments register-prefetched one tap
// ahead via a period-3 ring (9 taps % 3 == 0 keeps the ring aligned across
// ct, so all indices are compile-time). Swizzle fix: chunk = quad^((x>>1)&3)
// makes every 8-lane phase of the b128 read hit all 8 bank-quads ->
// conflict-free (old quad^(x&3) had a structural 2-way = +4 cyc/read,
// SQ_LDS_BANK_CONFLICT 9.4M). A-ring depth 2. One barrier per ct.
// XCD swizzle: lin&7 = batch b.
__global__ __launch_bounds__(256, 2) void k_conv(const u16* __restrict__ in_t,
                                                 const u16* __restrict__ w_t,
                                                 const float* __restrict__ demod_buf,
                                                 float* __restrict__ out) {
  __shared__ char smem[49152]; // B: 3 x 16 KB ring
  const int tid = threadIdx.x;
  const int lane = tid & 63;
  const int wv = tid >> 6;
  const int wm = wv >> 1, wn = wv & 1;
  const int quad = lane >> 4, m16 = lane & 15;
  const int lin = blockIdx.x + 32 * blockIdx.y + 128 * blockIdx.z; // [0,1024)
  const int b = lin & 7;
  const int r_ = lin >> 3;   // [0,128)
  const int nt = r_ & 31;
  const int mt = r_ >> 5;    // [0,4)
  const int y0 = nt * 2;

  floatx4 acc[4][4];
#pragma unroll
  for (int i = 0; i < 4; ++i)
#pragma unroll
    for (int j = 0; j < 4; ++j) acc[i][j] = (floatx4){0.f, 0.f, 0.f, 0.f};

  // per-lane A base (u16 elements); af(tap,ct,ms) = abase + ((tap*16+ct)<<14) + ms*512
  const u16* abase = w_t + mt * 4096 + wm * 2048 + lane * 8;

// async-stage B tile for channel-tile ct_ into LDS buffer Bbuf.
// LDS slot qi of row (r,x) holds global c-block qi^((x>>1)&3).
#define STAGE_B(ct_, Bbuf)                                                   \
  {                                                                          \
    const int c0s = (ct_)*32;                                                \
    _Pragma("unroll") for (int r = 0; r < 4; ++r) {                          \
      const int ci = r * 256 + tid;                                          \
      const int s = ci >> 2, qi = ci & 3;                                    \
      const int x = s & 63;                                                  \
      const int y = y0 - 1 + r;                                              \
      const int qd = qi ^ ((x >> 1) & 3);                                    \
      char* lbase = (Bbuf) + (r * 4 + wv) * 1024;                            \
      if ((unsigned)y < 64u) {                                               \
        const u16* g =                                                       \
            in_t + (((size_t)(b * 64 + y) * 64 + x) * 512 + c0s + qd * 8);   \
        GLD16(g, lbase);                                                     \
      } else {                                                               \
        *(uint4*)((Bbuf) + ci * 16) = make_uint4(0u, 0u, 0u, 0u);            \
      }                                                                      \
    }                                                                        \
  }

// load A fragments (4 x bf16x8) for (tap_, ct_) into ring slot dst
#define LOAD_A(tap_, ct_, dst)                                               \
  {                                                                          \
    const u16* ap_ = abase + ((size_t)((tap_)*16 + (ct_)) << 14);            \
    _Pragma("unroll") for (int ms = 0; ms < 4; ++ms)                         \
      (dst)[ms] = *(const bf16x8*)(ap_ + ms * 512);                          \
  }

// load B fragments (4 x bf16x8) for tap t_ from LDS buffer Bsrc into dst
#define LOAD_BV(dst, Bsrc, t_)                                               \
  {                                                                          \
    const int dy_ = (t_) / 3, dx_ = (t_) % 3;                                \
    _Pragma("unroll") for (int ns = 0; ns < 4; ++ns) {                       \
      const int nl = wn * 64 + ns * 16 + m16;                                \
      const int ly = nl >> 6, lx = nl & 63;                                  \
      const int sx = lx + dx_ - 1;                                           \
      if ((unsigned)sx < 64u) {                                              \
        const int s = (ly + dy_) * 64 + sx;                                  \
        (dst)[ns] = *(const bf16x8*)((Bsrc) + s * 64 +                       \
                                     ((quad ^ ((sx >> 1) & 3)) << 4));       \
      } else {                                                               \
        _Pragma("unroll") for (int j = 0; j < 8; ++j) (dst)[ns][j] =         \
            (bf16_t)0.f;                                                     \
      }                                                                      \
    }                                                                        \
  }

// one tap-step: prefetch A (2 ahead) + B (1 ahead), then 16 MFMAs on regs
#define T_BODY(t_, BCUR, BNXT, ACUR, ANXT)                                   \
  {                                                                          \
    const int tp_ = ((t_) + 2 <= 8) ? (t_) + 2 : (t_)-7;                     \
    const int ctp_ = ((t_) + 2 <= 8) ? ct : ((ct + 1) & 15);                 \
    LOAD_A(tp_, ctp_, ANXT);                                                 \
    if ((t_) < 8) {                                                          \
      LOAD_BV(BNXT, Bs, (t_) + 1);                                           \
    } else {                                                                 \
      LOAD_BV(BNXT, Bn, 0); /* next ct tap0; staged 2 cts ago, synced */     \
    }                                                                        \
    __builtin_amdgcn_s_setprio(1);                                           \
    _Pragma("unroll") for (int ns = 0; ns < 4; ++ns) {                       \
      _Pragma("unroll") for (int ms = 0; ms < 4; ++ms)                       \
        acc[ms][ns] = __builtin_amdgcn_mfma_f32_16x16x32_bf16(               \
            (ACUR)[ms], (BCUR)[ns], acc[ms][ns], 0, 0, 0);                   \
    }                                                                        \
    __builtin_amdgcn_s_setprio(0);                                           \
  }

  // ---- prologue: B(0), B(1) staged; A taps 0,1 of ct 0 in flight ----
  STAGE_B(0, smem);
  STAGE_B(1, smem + 16384);
  bf16x8 aR0[4], aR1[4], aR2[4];
  LOAD_A(0, 0, aR0);
  LOAD_A(1, 0, aR1);
  __syncthreads();

  bf16x8 bv0[4], bv1[4], bv2[4];
  {
    char* Bs = smem;
    LOAD_BV(bv0, Bs, 0);
  }

  char* Bs = smem;               // buffer for current ct
  char* Bn = smem + 16384;       // buffer for ct+1 (already staged+synced)
  char* Bs2 = smem + 32768;      // buffer being staged for ct+2
  for (int ct = 0; ct < 16; ++ct) {
    if (ct < 14) STAGE_B(ct + 2, Bs2);
#pragma unroll
    for (int t = 0; t < 9; ++t) {
      if (t % 3 == 0) {
        T_BODY(t, bv0, bv1, aR0, aR2);
      } else if (t % 3 == 1) {
        T_BODY(t, bv1, bv2, aR1, aR0);
      } else {
        T_BODY(t, bv2, bv0, aR2, aR1);
      }
    }
    __syncthreads(); // drains STAGE_B(ct+2); all reads of Bs done -> rotate
    char* tmp = Bs;
    Bs = Bn;
    Bn = Bs2;
    Bs2 = tmp;
  }

#undef STAGE_B
#undef LOAD_A
#undef LOAD_BV
#undef T_BODY

  // epilogue: D[m=quad*4+r][n=lane&15], scale by demod[b,o], f32 out
  const int ob = mt * 128 + wm * 64;
  const int nb = nt * 128 + wn * 64;
#pragma unroll
  for (int ms = 0; ms < 4; ++ms)
#pragma unroll
    for (int ns = 0; ns < 4; ++ns) {
      const int n = nb + ns * 16 + m16;
#pragma unroll
      for (int r = 0; r < 4; ++r) {
        const int o = ob + ms * 16 + quad * 4 + r;
        float dm = demod_buf[b * 512 + o];
        out[((size_t)(b * 512 + o) << 12) + n] = acc[ms][ns][r] * dm;
      }
    }
}

// ---------------------------------------------------------------------------
extern "C" void kernel_launch(void* const* d_in, const int* in_sizes, int n_in,
                              void* d_out, int out_size, void* d_ws, size_t ws_size,
                              hipStream_t stream) {
  const float* input = (const float*)d_in[0];   // [8,512,64,64] f32
  const float* style = (const float*)d_in[1];   // [8,512] f32
  const float* weight = (const float*)d_in[2];  // [1,512,512,3,3] f32
  const float* modw = (const float*)d_in[3];    // [512,512] f32
  const float* modb = (const float*)d_in[4];    // [512] f32
  float* out = (float*)d_out;                   // [8,512,64,64] f32
  char* ws = (char*)d_ws;
  float* s_buf = (float*)ws;                             // 16 KB
  float* demod_buf = (float*)(ws + 16384);               // 16 KB
  float* ssq = (float*)(ws + 32768);                     // 1 MB
  u16* in_t = (u16*)(ws + 32768 + 1048576);              // NHWC bf16, 33.5 MB
  u16* w_t = (u16*)(ws + 32768 + 1048576 + 33554432);    // frag bf16, 4.7 MB

  k_prep1<<<dim3(2048), dim3(256), 0, stream>>>(style, modw, modb, weight, s_buf, ssq);
  k_demod2<<<dim3(1024), dim3(256), 0, stream>>>(ssq, s_buf, demod_buf);
  k_transpose<<<dim3(8, 64, 8), dim3(256), 0, stream>>>(input, s_buf, (unsigned*)in_t);
  k_wfrag<<<dim3(16, 32), dim3(256), 0, stream>>>(weight, (unsigned*)w_t);
  k_conv<<<dim3(32, 4, 8), dim3(256), 0, stream>>>(in_t, w_t, demod_buf, out);
}

// Round 5
// 253.572 us; speedup vs baseline: 1.7764x; 1.0065x over previous
//
#include <hip/hip_runtime.h>

typedef unsigned short u16;
typedef __bf16 bf16_t;
typedef bf16_t bf16x8 __attribute__((ext_vector_type(8)));
typedef float floatx4 __attribute__((ext_vector_type(4)));

static constexpr float kScale = 0.014731391274719741f;    // 1/sqrt(512*9)
static constexpr float kScale2 = 2.1701388888888894e-4f;  // 1/(512*9)
static constexpr float kLinScale = 0.044194173824159216f; // 1/sqrt(512)

__device__ __forceinline__ u16 f2bf(float f) {
  unsigned u = __float_as_uint(f);
  u += 0x7FFFu + ((u >> 16) & 1u);
  return (u16)(u >> 16);
}

// async 16B global->LDS; LDS dst semantics: wave-uniform base + lane*16
#define GLD16(g, l)                                                        \
  __builtin_amdgcn_global_load_lds(                                        \
      (const __attribute__((address_space(1))) unsigned int*)(g),          \
      (__attribute__((address_space(3))) unsigned int*)(l), 16, 0, 0)

// ---------------------------------------------------------------------------
// Fused prep: blocks [0,1024): s[b,c] = style.modw^T*lin + bias
//             blocks [1024,2048): ssq[o,c] = sum_tap w^2
__global__ __launch_bounds__(256) void k_prep1(const float* __restrict__ style,
                                               const float* __restrict__ modw,
                                               const float* __restrict__ modb,
                                               const float* __restrict__ weight,
                                               float* __restrict__ s_buf,
                                               float* __restrict__ ssq) {
  int tid = threadIdx.x;
  if (blockIdx.x < 1024) {
    int lane = tid & 63, wv = tid >> 6;
    int idx = blockIdx.x * 4 + wv; // [0,4096)
    int b = idx >> 9, c = idx & 511;
    const float* st = style + b * 512;
    const float* mw = modw + (size_t)c * 512;
    float s = 0.f;
#pragma unroll
    for (int i = 0; i < 8; ++i) s += st[lane + i * 64] * mw[lane + i * 64];
#pragma unroll
    for (int off = 32; off; off >>= 1) s += __shfl_xor(s, off);
    if (lane == 0) s_buf[idx] = s * kLinScale + modb[c];
  } else {
    int e = (blockIdx.x - 1024) * 256 + tid; // [0, 262144)
    const float* wp = weight + (size_t)e * 9;
    float ss = 0.f;
#pragma unroll
    for (int t = 0; t < 9; ++t) ss += wp[t] * wp[t];
    ssq[e] = ss;
  }
}

// ---------------------------------------------------------------------------
// demod[b,o] = rsqrt( kScale^2 * sum_c ssq[o,c]*s[b,c]^2 + eps )
__global__ __launch_bounds__(256) void k_demod2(const float* __restrict__ ssq,
                                                const float* __restrict__ s_buf,
                                                float* __restrict__ demod_buf) {
  int tid = threadIdx.x, lane = tid & 63, wv = tid >> 6;
  int idx = blockIdx.x * 4 + wv; // [0,4096)
  int b = idx >> 9, o = idx & 511;
  const float* sq = ssq + (size_t)o * 512;
  const float* srow = s_buf + b * 512;
  float ss = 0.f;
#pragma unroll
  for (int i = 0; i < 8; ++i) {
    float s = srow[lane + i * 64];
    ss += sq[lane + i * 64] * s * s;
  }
#pragma unroll
  for (int off = 32; off; off >>= 1) ss += __shfl_xor(ss, off);
  if (lane == 0) demod_buf[idx] = rsqrtf(ss * kScale2 + 1e-8f);
}

// ---------------------------------------------------------------------------
// NCHW f32 -> NHWC bf16 with fused per-channel modulation:
// in_t[b,y,x,c] = bf16( in[b,c,y,x] * s[b,c] )
__global__ __launch_bounds__(256) void k_transpose(const float* __restrict__ in,
                                                   const float* __restrict__ s_buf,
                                                   unsigned* __restrict__ in_t32) {
  __shared__ u16 tile[64 * 65];
  int tid = threadIdx.x;
  int c0 = blockIdx.x * 64, y = blockIdx.y, b = blockIdx.z;
  const float* src = in + ((size_t)(b * 512 + c0) * 4096) + y * 64;
  const float* srow = s_buf + b * 512 + c0;
#pragma unroll
  for (int it = 0; it < 16; ++it) {
    int idx = it * 256 + tid;
    int cl = idx >> 6, x = idx & 63;
    tile[cl * 65 + x] = f2bf(src[(size_t)cl * 4096 + x] * srow[cl]);
  }
  __syncthreads();
  unsigned* dst = in_t32 + ((size_t)(b * 64 + y) * 64) * 256 + (c0 >> 1);
#pragma unroll
  for (int it = 0; it < 8; ++it) {
    int flat = it * 256 + tid; // [0,2048)
    int cl2 = flat & 31, x = flat >> 5;
    unsigned lo = tile[(2 * cl2) * 65 + x];
    unsigned hi = tile[(2 * cl2 + 1) * 65 + x];
    dst[(size_t)x * 256 + cl2] = lo | (hi << 16);
  }
}

// ---------------------------------------------------------------------------
// Batch-independent weight fragments: w_frag[tap][ct][ot][512] = kScale * w,
// pos = (o_l + 16*(c_l>>3))*8 + (c_l&7). Only 4.7 MB.
__global__ __launch_bounds__(256) void k_wfrag(const float* __restrict__ weight,
                                               unsigned* __restrict__ wt32) {
  __shared__ u16 tiles[9][512];
  int tid = threadIdx.x;
  int ct = blockIdx.x, ot = blockIdx.y;
  int o0 = ot * 16, c0 = ct * 32;
#pragma unroll
  for (int i = 0; i < 18; ++i) {
    int flat = i * 256 + tid;         // [0,4608) = o_l*288 + c_l*9 + tap
    int t9 = flat / 9;
    int tap = flat - t9 * 9;
    int o_l = t9 >> 5, c_l = t9 & 31;
    float w = weight[((size_t)(o0 + o_l) * 512 + c0 + c_l) * 9 + tap];
    int pos = ((o_l + ((c_l >> 3) << 4)) << 3) + (c_l & 7);
    tiles[tap][pos] = f2bf(w * kScale);
  }
  __syncthreads();
  const unsigned* tl = (const unsigned*)tiles;
#pragma unroll
  for (int tap = 0; tap < 9; ++tap)
    wt32[(size_t)((tap * 16 + ct) * 32 + ot) * 256 + tid] = tl[tap * 256 + tid];
}

// ---------------------------------------------------------------------------
// Implicit-GEMM conv, occupancy+VALU round:
//  - B tile x-PADDED to 66 cols (zeroed once) -> no divergent OOB handling.
//  - B ds addresses hoisted to 3 VGPRs (per dx); ns(+1024)/dy(+4224)/buffer
//    (+16896) are compile-time ds_read immediates (ct unrolled x2 for buffer
//    parity). LOAD_BV = 4 raw ds_read_b128, ~0 VALU.
//  - rings: aR[2], bv[2] (parity via ct x2 unroll); LDS 2 x 16896 = 33 KB.
//  - __launch_bounds__(256,3): ~153 regs/wave (89 VGPR + 64 AGPR) -> 3
//    blocks/CU (12 waves), 50% more MFMA work per window than R4.
//  - counted-vmcnt barrier (T4): s_waitcnt vmcnt(4) + raw s_barrier per ct;
//    stage(ct+1) issued at ct start stays in flight through the t-loop.
// XCD swizzle: lin&7 = batch b.
__global__ __launch_bounds__(256, 3) void k_conv(const u16* __restrict__ in_t,
                                                 const u16* __restrict__ w_t,
                                                 const float* __restrict__ demod_buf,
                                                 float* __restrict__ out) {
  __shared__ char smem[33792]; // 2 buffers x (4 rows x 66 cols x 64 B = 16896)
  const int tid = threadIdx.x;
  const int lane = tid & 63;
  const int wv = tid >> 6;
  const int wm = wv >> 1, wn = wv & 1;
  const int quad = lane >> 4, m16 = lane & 15;
  const int lin = blockIdx.x + 32 * blockIdx.y + 128 * blockIdx.z; // [0,1024)
  const int b = lin & 7;
  const int r_ = lin >> 3;   // [0,128)
  const int nt = r_ & 31;
  const int mt = r_ >> 5;    // [0,4)
  const int y0 = nt * 2;

  floatx4 acc[4][4];
#pragma unroll
  for (int i = 0; i < 4; ++i)
#pragma unroll
    for (int j = 0; j < 4; ++j) acc[i][j] = (floatx4){0.f, 0.f, 0.f, 0.f};

  // per-lane A base (u16); A(tap,ct) frag ms at abase + ((tap*16+ct)<<14) + ms*512
  const u16* abase = w_t + mt * 4096 + wm * 2048 + lane * 8;

  // B global row pointers (r=0..3); advanced +32 ch (=64 B) per ct
  const int xs = tid >> 2, qs = tid & 3;
  const int qd = qs ^ ((xs >> 1) & 3);
  const u16* gB[4];
  bool rok[4];
#pragma unroll
  for (int r = 0; r < 4; ++r) {
    int y = y0 - 1 + r;
    rok[r] = (unsigned)y < 64u; // block-uniform
    gB[r] = in_t + (((size_t)(b * 64 + (rok[r] ? y : 0)) * 64 + xs) * 512 + qd * 8);
  }

  // B read base addresses, one per dx. row=(wn+dy), addr = row*4224 +
  // (sx+1)*64 + (quad^((sx>>1)&3))*16, sx = ns*16+m16+dx-1; ns-step = +1024
  // exactly ((sx>>1)&3 invariant under +16), dy-step = +4224.
  char* bA[3];
#pragma unroll
  for (int dx = 0; dx < 3; ++dx) {
    const int sx0 = m16 + dx - 1;
    bA[dx] = smem + wn * 4224 + (sx0 + 1) * 64 + ((quad ^ ((sx0 >> 1) & 3)) << 4);
  }

  bf16x8 aR[2][4];
  bf16x8 bv[2][4];

#define LOAD_BV(si, bufimm, t_)                                              \
  {                                                                          \
    const int dy_ = (t_) / 3, dx_ = (t_) % 3;                                \
    _Pragma("unroll") for (int ns = 0; ns < 4; ++ns)                         \
      bv[si][ns] = *(const bf16x8*)(bA[dx_] + (bufimm) + dy_ * 4224 +        \
                                    ns * 1024);                              \
  }

#define STAGE_B(bufimm)                                                      \
  {                                                                          \
    _Pragma("unroll") for (int r = 0; r < 4; ++r)                            \
      if (rok[r]) GLD16(gB[r], smem + (bufimm) + r * 4224 + 64 + wv * 1024); \
  }

// one ct: top bv load (from buffer confirmed at prev barrier), stage next ct,
// 9 tap-steps (A prefetch depth-1, B-frag prefetch depth-1), counted barrier.
#define CT_BODY(ctv, par, CURIMM, NXTIMM)                                    \
  {                                                                          \
    LOAD_BV(par, CURIMM, 0);                                                 \
    if ((ctv) + 1 < 16) {                                                    \
      _Pragma("unroll") for (int r = 0; r < 4; ++r) gB[r] += 32;             \
      STAGE_B(NXTIMM);                                                       \
    }                                                                        \
    _Pragma("unroll") for (int t = 0; t < 9; ++t) {                          \
      const int icur = (t + (par)) & 1;                                      \
      const int inxt = icur ^ 1;                                             \
      const int tp = t < 8 ? t + 1 : 0;                                      \
      const int ctp = t < 8 ? (ctv) : (ctv) + 1;                             \
      const u16* ap = abase + ((size_t)(tp * 16 + ctp) << 14);               \
      _Pragma("unroll") for (int ms = 0; ms < 4; ++ms)                       \
        aR[inxt][ms] = *(const bf16x8*)(ap + ms * 512);                      \
      if (t < 8) { LOAD_BV(inxt, CURIMM, t + 1); }                           \
      __builtin_amdgcn_s_setprio(1);                                         \
      _Pragma("unroll") for (int ns = 0; ns < 4; ++ns)                       \
        _Pragma("unroll") for (int ms = 0; ms < 4; ++ms)                     \
          acc[ms][ns] = __builtin_amdgcn_mfma_f32_16x16x32_bf16(             \
              aR[icur][ms], bv[icur][ns], acc[ms][ns], 0, 0, 0);             \
      __builtin_amdgcn_s_setprio(0);                                         \
    }                                                                        \
    asm volatile("s_waitcnt vmcnt(4)" ::: "memory");                         \
    __builtin_amdgcn_s_barrier();                                            \
  }

  // ---- prologue: zero LDS (pads + OOB rows), stage ct=0, load A(0,0) ----
  {
    const uint4 z = make_uint4(0u, 0u, 0u, 0u);
    for (int i = tid; i < 2112; i += 256) ((uint4*)smem)[i] = z;
  }
  __syncthreads();
  STAGE_B(0);
  __syncthreads(); // drains stage(0) (vmcnt 0) + makes zeros visible
#pragma unroll
  for (int ms = 0; ms < 4; ++ms)
    aR[0][ms] = *(const bf16x8*)(abase + ms * 512);

  for (int ct = 0; ct < 16; ct += 2) {
    CT_BODY(ct, 0, 0, 16896);
    CT_BODY(ct + 1, 1, 16896, 0);
  }

#undef LOAD_BV
#undef STAGE_B
#undef CT_BODY

  // epilogue: D[m=quad*4+r][n=lane&15], scale by demod[b,o], f32 out
  const int ob = mt * 128 + wm * 64;
  const int nb = nt * 128 + wn * 64;
#pragma unroll
  for (int ms = 0; ms < 4; ++ms)
#pragma unroll
    for (int ns = 0; ns < 4; ++ns) {
      const int n = nb + ns * 16 + m16;
#pragma unroll
      for (int r = 0; r < 4; ++r) {
        const int o = ob + ms * 16 + quad * 4 + r;
        float dm = demod_buf[b * 512 + o];
        out[((size_t)(b * 512 + o) << 12) + n] = acc[ms][ns][r] * dm;
      }
    }
}

// ---------------------------------------------------------------------------
extern "C" void kernel_launch(void* const* d_in, const int* in_sizes, int n_in,
                              void* d_out, int out_size, void* d_ws, size_t ws_size,
                              hipStream_t stream) {
  const float* input = (const float*)d_in[0];   // [8,512,64,64] f32
  const float* style = (const float*)d_in[1];   // [8,512] f32
  const float* weight = (const float*)d_in[2];  // [1,512,512,3,3] f32
  const float* modw = (const float*)d_in[3];    // [512,512] f32
  const float* modb = (const float*)d_in[4];    // [512] f32
  float* out = (float*)d_out;                   // [8,512,64,64] f32
  char* ws = (char*)d_ws;
  float* s_buf = (float*)ws;                             // 16 KB
  float* demod_buf = (float*)(ws + 16384);               // 16 KB
  float* ssq = (float*)(ws + 32768);                     // 1 MB
  u16* in_t = (u16*)(ws + 32768 + 1048576);              // NHWC bf16, 33.5 MB
  u16* w_t = (u16*)(ws + 32768 + 1048576 + 33554432);    // frag bf16, 4.7 MB

  k_prep1<<<dim3(2048), dim3(256), 0, stream>>>(style, modw, modb, weight, s_buf, ssq);
  k_demod2<<<dim3(1024), dim3(256), 0, stream>>>(ssq, s_buf, demod_buf);
  k_transpose<<<dim3(8, 64, 8), dim3(256), 0, stream>>>(input, s_buf, (unsigned*)in_t);
  k_wfrag<<<dim3(16, 32), dim3(256), 0, stream>>>(weight, (unsigned*)w_t);
  k_conv<<<dim3(32, 4, 8), dim3(256), 0, stream>>>(in_t, w_t, demod_buf, out);
}

// Round 6
// 249.270 us; speedup vs baseline: 1.8071x; 1.0173x over previous
//
#include <hip/hip_runtime.h>

typedef unsigned short u16;
typedef __bf16 bf16_t;
typedef bf16_t bf16x8 __attribute__((ext_vector_type(8)));
typedef float floatx4 __attribute__((ext_vector_type(4)));

static constexpr float kScale = 0.014731391274719741f;    // 1/sqrt(512*9)
static constexpr float kScale2 = 2.1701388888888894e-4f;  // 1/(512*9)
static constexpr float kLinScale = 0.044194173824159216f; // 1/sqrt(512)

__device__ __forceinline__ u16 f2bf(float f) {
  unsigned u = __float_as_uint(f);
  u += 0x7FFFu + ((u >> 16) & 1u);
  return (u16)(u >> 16);
}

// async 16B global->LDS; LDS dst semantics: wave-uniform base + lane*16
#define GLD16(g, l)                                                        \
  __builtin_amdgcn_global_load_lds(                                        \
      (const __attribute__((address_space(1))) unsigned int*)(g),          \
      (__attribute__((address_space(3))) unsigned int*)(l), 16, 0, 0)

// ---------------------------------------------------------------------------
// Fused prep: blocks [0,1024): s[b,c] = style.modw^T*lin + bias
//             blocks [1024,2048): ssq[o,c] = sum_tap w^2
__global__ __launch_bounds__(256) void k_prep1(const float* __restrict__ style,
                                               const float* __restrict__ modw,
                                               const float* __restrict__ modb,
                                               const float* __restrict__ weight,
                                               float* __restrict__ s_buf,
                                               float* __restrict__ ssq) {
  int tid = threadIdx.x;
  if (blockIdx.x < 1024) {
    int lane = tid & 63, wv = tid >> 6;
    int idx = blockIdx.x * 4 + wv; // [0,4096)
    int b = idx >> 9, c = idx & 511;
    const float* st = style + b * 512;
    const float* mw = modw + (size_t)c * 512;
    float s = 0.f;
#pragma unroll
    for (int i = 0; i < 8; ++i) s += st[lane + i * 64] * mw[lane + i * 64];
#pragma unroll
    for (int off = 32; off; off >>= 1) s += __shfl_xor(s, off);
    if (lane == 0) s_buf[idx] = s * kLinScale + modb[c];
  } else {
    int e = (blockIdx.x - 1024) * 256 + tid; // [0, 262144)
    const float* wp = weight + (size_t)e * 9;
    float ss = 0.f;
#pragma unroll
    for (int t = 0; t < 9; ++t) ss += wp[t] * wp[t];
    ssq[e] = ss;
  }
}

// ---------------------------------------------------------------------------
// demod[b,o] = rsqrt( kScale^2 * sum_c ssq[o,c]*s[b,c]^2 + eps )
__global__ __launch_bounds__(256) void k_demod2(const float* __restrict__ ssq,
                                                const float* __restrict__ s_buf,
                                                float* __restrict__ demod_buf) {
  int tid = threadIdx.x, lane = tid & 63, wv = tid >> 6;
  int idx = blockIdx.x * 4 + wv; // [0,4096)
  int b = idx >> 9, o = idx & 511;
  const float* sq = ssq + (size_t)o * 512;
  const float* srow = s_buf + b * 512;
  float ss = 0.f;
#pragma unroll
  for (int i = 0; i < 8; ++i) {
    float s = srow[lane + i * 64];
    ss += sq[lane + i * 64] * s * s;
  }
#pragma unroll
  for (int off = 32; off; off >>= 1) ss += __shfl_xor(ss, off);
  if (lane == 0) demod_buf[idx] = rsqrtf(ss * kScale2 + 1e-8f);
}

// ---------------------------------------------------------------------------
// NCHW f32 -> NHWC bf16 with fused per-channel modulation:
// in_t[b,y,x,c] = bf16( in[b,c,y,x] * s[b,c] )
__global__ __launch_bounds__(256) void k_transpose(const float* __restrict__ in,
                                                   const float* __restrict__ s_buf,
                                                   unsigned* __restrict__ in_t32) {
  __shared__ u16 tile[64 * 65];
  int tid = threadIdx.x;
  int c0 = blockIdx.x * 64, y = blockIdx.y, b = blockIdx.z;
  const float* src = in + ((size_t)(b * 512 + c0) * 4096) + y * 64;
  const float* srow = s_buf + b * 512 + c0;
#pragma unroll
  for (int it = 0; it < 16; ++it) {
    int idx = it * 256 + tid;
    int cl = idx >> 6, x = idx & 63;
    tile[cl * 65 + x] = f2bf(src[(size_t)cl * 4096 + x] * srow[cl]);
  }
  __syncthreads();
  unsigned* dst = in_t32 + ((size_t)(b * 64 + y) * 64) * 256 + (c0 >> 1);
#pragma unroll
  for (int it = 0; it < 8; ++it) {
    int flat = it * 256 + tid; // [0,2048)
    int cl2 = flat & 31, x = flat >> 5;
    unsigned lo = tile[(2 * cl2) * 65 + x];
    unsigned hi = tile[(2 * cl2 + 1) * 65 + x];
    dst[(size_t)x * 256 + cl2] = lo | (hi << 16);
  }
}

// ---------------------------------------------------------------------------
// Batch-independent weight fragments: w_frag[tap][ct][ot][512] = kScale * w,
// pos = (o_l + 16*(c_l>>3))*8 + (c_l&7). Only 4.7 MB.
__global__ __launch_bounds__(256) void k_wfrag(const float* __restrict__ weight,
                                               unsigned* __restrict__ wt32) {
  __shared__ u16 tiles[9][512];
  int tid = threadIdx.x;
  int ct = blockIdx.x, ot = blockIdx.y;
  int o0 = ot * 16, c0 = ct * 32;
#pragma unroll
  for (int i = 0; i < 18; ++i) {
    int flat = i * 256 + tid;         // [0,4608) = o_l*288 + c_l*9 + tap
    int t9 = flat / 9;
    int tap = flat - t9 * 9;
    int o_l = t9 >> 5, c_l = t9 & 31;
    float w = weight[((size_t)(o0 + o_l) * 512 + c0 + c_l) * 9 + tap];
    int pos = ((o_l + ((c_l >> 3) << 4)) << 3) + (c_l & 7);
    tiles[tap][pos] = f2bf(w * kScale);
  }
  __syncthreads();
  const unsigned* tl = (const unsigned*)tiles;
#pragma unroll
  for (int tap = 0; tap < 9; ++tap)
    wt32[(size_t)((tap * 16 + ct) * 32 + ot) * 256 + tid] = tl[tap * 256 + tid];
}

// ---------------------------------------------------------------------------
// Implicit-GEMM conv, K=64-per-quantum round (stall amortization):
//  - each t-step now covers 64 channels (2 k-halves) = 32 MFMAs (620 cyc of
//    pipe) against one load/sync quantum, vs 16 MFMAs before. The pipe-audit
//    showed no pipe >60% busy -> latency-bound with ~2.67 waves/SIMD; longer
//    dependency-free runs are the only lever left at this register budget.
//  - B tile: 4 rows x 66 cols x 64 ch bf16 = 33 KB, double-buffered (67.5 KB
//    LDS -> 2 blocks/CU, grid 1024 = exactly 2 residency waves, no tail).
//  - cell = 128 B = 8 slots; swizzle slot = chunk ^ (x&7): conflict-free
//    b128 reads (8-lane phase covers all 8 slots), ns-step (+16 px = +2048 B)
//    slot-invariant -> 6 base VGPRs (3 dx x 2 kh), all else ds imm offsets.
//  - barriers halved (8 ct'-iterations); counted vmcnt(8) keeps the 8 A-loads
//    in flight across each barrier.
//  - regs: acc 64 AGPR + aR[2][2][4]+bv[2][2][4] = 128 VGPR + addr ~30 ->
//    ~220 unified, fits 2 waves/SIMD (cap 256). Spill tripwire: WRITE_SIZE.
// XCD swizzle: lin&7 = batch b.
__global__ __launch_bounds__(256, 2) void k_conv(const u16* __restrict__ in_t,
                                                 const u16* __restrict__ w_t,
                                                 const float* __restrict__ demod_buf,
                                                 float* __restrict__ out) {
  __shared__ char smem[67584]; // 2 buffers x (4 rows x 66 cells x 128 B)
  const int tid = threadIdx.x;
  const int lane = tid & 63;
  const int wv = tid >> 6;
  const int wm = wv >> 1, wn = wv & 1;
  const int quad = lane >> 4, m16 = lane & 15;
  const int lin = blockIdx.x + 32 * blockIdx.y + 128 * blockIdx.z; // [0,1024)
  const int b = lin & 7;
  const int r_ = lin >> 3;   // [0,128)
  const int nt = r_ & 31;
  const int mt = r_ >> 5;    // [0,4)
  const int y0 = nt * 2;

  floatx4 acc[4][4];
#pragma unroll
  for (int i = 0; i < 4; ++i)
#pragma unroll
    for (int j = 0; j < 4; ++j) acc[i][j] = (floatx4){0.f, 0.f, 0.f, 0.f};

  // per-lane A base (u16); A frag ms of (tap, ct32) at
  // abase + ((tap*16 + ct32)<<14) + ms*512, ct32 = 2*ct' + kh
  const u16* abase = w_t + mt * 4096 + wm * 2048 + lane * 8;

  // B stage source: thread covers slot chunk of cell xs (h=0: x 0..31;
  // h=1 adds +16384 u16 = +32 cells). Inverse swizzle on the source.
  const int xs = tid >> 3, qs = tid & 7;
  const int cch = qs ^ (xs & 7); // global 8-ch chunk stored at slot qs
  const u16* gB[4];
  bool rok[4];
#pragma unroll
  for (int r = 0; r < 4; ++r) {
    int y = y0 - 1 + r;
    rok[r] = (unsigned)y < 64u; // block-uniform
    gB[r] = in_t + (((size_t)(b * 64 + (rok[r] ? y : 0)) * 64 + xs) * 512 + cch * 8);
  }

  // B read bases, one per (dx, kh). row=(wn+dy):
  // addr = row*8448 + (sx+1)*128 + ((kh*4+quad)^(sx&7))*16,
  // sx = ns*16+m16+dx-1; ns-step = +2048 (slot invariant), dy-step = +8448.
  char* bA[6];
#pragma unroll
  for (int dx = 0; dx < 3; ++dx) {
    const int sx0 = m16 + dx - 1;
#pragma unroll
    for (int kh = 0; kh < 2; ++kh)
      bA[dx * 2 + kh] = smem + wn * 8448 + (sx0 + 1) * 128 +
                        (((kh * 4 + quad) ^ (sx0 & 7)) << 4);
  }

  bf16x8 aR[2][2][4];
  bf16x8 bv[2][2][4];

#define LOAD_BV(si, bufimm, t_)                                              \
  {                                                                          \
    const int dy_ = (t_) / 3, dx_ = (t_) % 3;                                \
    _Pragma("unroll") for (int kh = 0; kh < 2; ++kh)                         \
      _Pragma("unroll") for (int ns = 0; ns < 4; ++ns)                       \
        bv[si][kh][ns] = *(const bf16x8*)(bA[dx_ * 2 + kh] + (bufimm) +      \
                                          dy_ * 8448 + ns * 2048);           \
  }

#define STAGE_B(bufimm)                                                      \
  {                                                                          \
    _Pragma("unroll") for (int r = 0; r < 4; ++r)                            \
      if (rok[r]) {                                                          \
        GLD16(gB[r], smem + (bufimm) + r * 8448 + 128 + wv * 1024);          \
        GLD16(gB[r] + 16384,                                                 \
              smem + (bufimm) + r * 8448 + 128 + 4096 + wv * 1024);          \
      }                                                                      \
  }

#define LOAD_A2(si, tp_, ctp_)                                               \
  {                                                                          \
    _Pragma("unroll") for (int kh = 0; kh < 2; ++kh) {                       \
      const u16* ap_ =                                                       \
          abase + ((size_t)((tp_)*16 + 2 * (ctp_) + kh) << 14);              \
      _Pragma("unroll") for (int ms = 0; ms < 4; ++ms)                       \
        aR[si][kh][ms] = *(const bf16x8*)(ap_ + ms * 512);                   \
    }                                                                        \
  }

// one ct' (64 channels): 9 tap-steps of 32 MFMA; A+B frag prefetch depth 1;
// stage(ct'+1) in flight across the whole t-loop, drained by vmcnt(8).
#define CT_BODY(ctv, par, CURIMM, NXTIMM)                                    \
  {                                                                          \
    LOAD_BV(par, CURIMM, 0);                                                 \
    if ((ctv) + 1 < 8) {                                                     \
      _Pragma("unroll") for (int r = 0; r < 4; ++r) gB[r] += 64;             \
      STAGE_B(NXTIMM);                                                       \
    }                                                                        \
    _Pragma("unroll") for (int t = 0; t < 9; ++t) {                          \
      const int icur = (t + (par)) & 1;                                      \
      const int inxt = icur ^ 1;                                             \
      const int tp = t < 8 ? t + 1 : 0;                                      \
      const int ctp = t < 8 ? (ctv) : (ctv) + 1;                             \
      LOAD_A2(inxt, tp, ctp);                                                \
      if (t < 8) { LOAD_BV(inxt, CURIMM, t + 1); }                           \
      __builtin_amdgcn_s_setprio(1);                                         \
      _Pragma("unroll") for (int kh = 0; kh < 2; ++kh)                       \
        _Pragma("unroll") for (int ns = 0; ns < 4; ++ns)                     \
          _Pragma("unroll") for (int ms = 0; ms < 4; ++ms)                   \
            acc[ms][ns] = __builtin_amdgcn_mfma_f32_16x16x32_bf16(           \
                aR[icur][kh][ms], bv[icur][kh][ns], acc[ms][ns], 0, 0, 0);   \
      __builtin_amdgcn_s_setprio(0);                                         \
    }                                                                        \
    asm volatile("s_waitcnt vmcnt(8)" ::: "memory");                         \
    __builtin_amdgcn_s_barrier();                                            \
  }

  // ---- prologue: zero LDS (pads + OOB rows), stage ct'=0, load A(0, 0|1) --
  {
    const uint4 z = make_uint4(0u, 0u, 0u, 0u);
    for (int i = tid; i < 4224; i += 256) ((uint4*)smem)[i] = z;
  }
  __syncthreads();
  STAGE_B(0);
  __syncthreads(); // drains stage(0) + makes zeros visible
  LOAD_A2(0, 0, 0);

  for (int ct = 0; ct < 8; ct += 2) {
    CT_BODY(ct, 0, 0, 33792);
    CT_BODY(ct + 1, 1, 33792, 0);
  }

#undef LOAD_BV
#undef STAGE_B
#undef LOAD_A2
#undef CT_BODY

  // epilogue: D[m=quad*4+r][n=lane&15], scale by demod[b,o], f32 out
  const int ob = mt * 128 + wm * 64;
  const int nb = nt * 128 + wn * 64;
#pragma unroll
  for (int ms = 0; ms < 4; ++ms)
#pragma unroll
    for (int ns = 0; ns < 4; ++ns) {
      const int n = nb + ns * 16 + m16;
#pragma unroll
      for (int r = 0; r < 4; ++r) {
        const int o = ob + ms * 16 + quad * 4 + r;
        float dm = demod_buf[b * 512 + o];
        out[((size_t)(b * 512 + o) << 12) + n] = acc[ms][ns][r] * dm;
      }
    }
}

// ---------------------------------------------------------------------------
extern "C" void kernel_launch(void* const* d_in, const int* in_sizes, int n_in,
                              void* d_out, int out_size, void* d_ws, size_t ws_size,
                              hipStream_t stream) {
  const float* input = (const float*)d_in[0];   // [8,512,64,64] f32
  const float* style = (const float*)d_in[1];   // [8,512] f32
  const float* weight = (const float*)d_in[2];  // [1,512,512,3,3] f32
  const float* modw = (const float*)d_in[3];    // [512,512] f32
  const float* modb = (const float*)d_in[4];    // [512] f32
  float* out = (float*)d_out;                   // [8,512,64,64] f32
  char* ws = (char*)d_ws;
  float* s_buf = (float*)ws;                             // 16 KB
  float* demod_buf = (float*)(ws + 16384);               // 16 KB
  float* ssq = (float*)(ws + 32768);                     // 1 MB
  u16* in_t = (u16*)(ws + 32768 + 1048576);              // NHWC bf16, 33.5 MB
  u16* w_t = (u16*)(ws + 32768 + 1048576 + 33554432);    // frag bf16, 4.7 MB

  k_prep1<<<dim3(2048), dim3(256), 0, stream>>>(style, modw, modb, weight, s_buf, ssq);
  k_demod2<<<dim3(1024), dim3(256), 0, stream>>>(ssq, s_buf, demod_buf);
  k_transpose<<<dim3(8, 64, 8), dim3(256), 0, stream>>>(input, s_buf, (unsigned*)in_t);
  k_wfrag<<<dim3(16, 32), dim3(256), 0, stream>>>(weight, (unsigned*)w_t);
  k_conv<<<dim3(32, 4, 8), dim3(256), 0, stream>>>(in_t, w_t, demod_buf, out);
}